// Round 13
// baseline (342.212 us; speedup 1.0000x reference)
//
#include <hip/hip_runtime.h>
#include <hip/hip_bf16.h>
#include <hip/hip_fp16.h>
#include <math.h>

#define N_NODES 10000
#define N_EDGES 160000
#define E_TOT   (N_EDGES + N_NODES)
#define F_IN    300
#define D       1024
#define N_CLS   10
#define NEG_SLOPE 0.2f

#define MP      10112              // 79 * 128, padded M
#define KP1     320                // F_IN padded to mult of 32
#define KP2     1024
#define WCAP    1024               // weight-cache capacity (deg ~ Poisson(17))

typedef __attribute__((ext_vector_type(8))) _Float16 f16x8;
typedef __attribute__((ext_vector_type(4))) float f32x4;

#define GLOAD_LDS16(g, l) __builtin_amdgcn_global_load_lds( \
    (const __attribute__((address_space(1))) void*)(g), \
    (__attribute__((address_space(3))) void*)(l), 16, 0, 0)

// ---------------- CSR build (count/scan/scatter; deg init in mega_prep) ----------------

__global__ void count_edges(const int* __restrict__ dst, int* __restrict__ deg) {
    int e = blockIdx.x * blockDim.x + threadIdx.x;
    if (e < N_EDGES) atomicAdd(&deg[dst[e]], 1);
}

__global__ void scan_offs(const int* __restrict__ deg, int* __restrict__ offs,
                          int* __restrict__ pos) {
    __shared__ int sbuf[1024];
    __shared__ int scarry;
    int t = threadIdx.x;
    if (t == 0) { scarry = 0; offs[0] = 0; }
    __syncthreads();
    for (int base = 0; base < N_NODES; base += 1024) {
        int v = (base + t < N_NODES) ? deg[base + t] : 0;
        sbuf[t] = v;
        __syncthreads();
        for (int off = 1; off < 1024; off <<= 1) {
            int add = (t >= off) ? sbuf[t - off] : 0;
            __syncthreads();
            sbuf[t] += add;
            __syncthreads();
        }
        int carry = scarry;
        if (base + t < N_NODES) {
            int incl = carry + sbuf[t];
            offs[base + t + 1] = incl;
            pos[base + t]      = incl - v;
        }
        __syncthreads();
        if (t == 1023) scarry = carry + sbuf[1023];
        __syncthreads();
    }
}

__global__ void scatter_edges(const int* __restrict__ src, const int* __restrict__ dst,
                              int* __restrict__ pos, int* __restrict__ ssrc) {
    int e = blockIdx.x * blockDim.x + threadIdx.x;
    if (e < N_EDGES) {
        int d = dst[e];
        int p = atomicAdd(&pos[d], 1);
        ssrc[p] = src[e];
    } else if (e < E_TOT) {
        int i = e - N_EDGES;
        int p = atomicAdd(&pos[i], 1);
        ssrc[p] = i;
    }
}

// ---------------- mega_prep: prep_uv | transpose W1 | transpose W2 | zeros+deg ----------------

#define ZR1 (112 * KP1)        // asplit1 pad rows, per plane
#define ZR2 (N_NODES * 20)     // asplit1 pad cols (300..319), per plane
#define ZR3 (112 * KP2)        // asplit2 pad rows, per plane
#define ZTOT (2*ZR1 + 2*ZR2 + 2*ZR3 + 2*N_NODES)

#define ZONE_A 331             // prep_uv: (F_IN+D)*64/256 waves
#define ZONE_B 320             // transpose W1: (KP1/32)*(D/32)
#define ZONE_C 1024            // transpose W2: (KP2/32)*(D/32)
#define ZONE_D ((ZTOT + N_NODES + 255) / 256)

__global__ __launch_bounds__(256) void mega_prep(
        const float* __restrict__ W1, const float* __restrict__ as1,
        const float* __restrict__ ad1, const float* __restrict__ W2,
        const float* __restrict__ as2, const float* __restrict__ ad2,
        float* __restrict__ u1, float* __restrict__ v1,
        float* __restrict__ u2, float* __restrict__ v2,
        _Float16* __restrict__ BT1h, _Float16* __restrict__ BT2h,
        float* __restrict__ hs2, float* __restrict__ hd2,
        unsigned short* __restrict__ Ah1, unsigned short* __restrict__ Al1,
        unsigned short* __restrict__ Ah2, unsigned short* __restrict__ Al2,
        int* __restrict__ deg) {
    __shared__ float tile[32][33];
    int b = blockIdx.x;
    int t = threadIdx.x;

    if (b < ZONE_A) {
        int wid  = (b * 256 + t) >> 6;
        int lane = t & 63;
        const float* row; const float* a; const float* bb; float *du, *dv; int k;
        if (wid < F_IN) {
            k = wid; row = W1 + (size_t)k * D; a = as1; bb = ad1; du = u1; dv = v1;
        } else {
            k = wid - F_IN; row = W2 + (size_t)k * D; a = as2; bb = ad2; du = u2; dv = v2;
        }
        float s1 = 0.f, s2 = 0.f;
        for (int n = lane; n < D; n += 64) {
            float w = row[n];
            s1 += w * a[n];
            s2 += w * bb[n];
        }
        #pragma unroll
        for (int o = 32; o; o >>= 1) { s1 += __shfl_xor(s1, o); s2 += __shfl_xor(s2, o); }
        if (lane == 0) { du[k] = s1; dv[k] = s2; }
        return;
    }
    if (b < ZONE_A + ZONE_B + ZONE_C) {
        if (b < ZONE_A + ZONE_B) {
            int b2 = b - ZONE_A;
            int kb = b2 % (KP1 / 32), nb = b2 / (KP1 / 32);
            int k0 = kb * 32, n0 = nb * 32;
            int tx = t & 31, ty = t >> 5;
            #pragma unroll
            for (int j = 0; j < 32; j += 8) {
                int k = k0 + ty + j;
                tile[ty + j][tx] = (k < F_IN) ? W1[(size_t)k * D + n0 + tx] : 0.f;
            }
            __syncthreads();
            #pragma unroll
            for (int j = 0; j < 32; j += 8)
                BT1h[(size_t)(n0 + ty + j) * KP1 + k0 + tx] = (_Float16)tile[tx][ty + j];
        } else {
            int b2 = b - ZONE_A - ZONE_B;
            int kb = b2 & 31, nb = b2 >> 5;
            int k0 = kb * 32, n0 = nb * 32;
            int tx = t & 31, ty = t >> 5;
            #pragma unroll
            for (int j = 0; j < 32; j += 8) {
                int k = k0 + ty + j;
                tile[ty + j][tx] = W2[(size_t)k * D + n0 + tx];
            }
            __syncthreads();
            #pragma unroll
            for (int j = 0; j < 32; j += 8)
                BT2h[(size_t)(n0 + ty + j) * KP2 + k0 + tx] = (_Float16)tile[tx][ty + j];
        }
        return;
    }
    // zone D: zeros + deg init
    int idx = (b - ZONE_A - ZONE_B - ZONE_C) * 256 + t;
    if (idx >= ZTOT + N_NODES) return;
    if (idx >= ZTOT) { deg[idx - ZTOT] = 1; return; }   // self loop
    if (idx < 2 * ZR1) {
        unsigned short* B = (idx < ZR1) ? Ah1 : Al1;
        int off = (idx < ZR1) ? idx : idx - ZR1;
        B[(size_t)N_NODES * KP1 + off] = 0;
    } else if ((idx -= 2 * ZR1) < 2 * ZR2) {
        unsigned short* B = (idx < ZR2) ? Ah1 : Al1;
        int off = (idx < ZR2) ? idx : idx - ZR2;
        int r = off / 20, c = 300 + off % 20;
        B[(size_t)r * KP1 + c] = 0;
    } else if ((idx -= 2 * ZR2) < 2 * ZR3) {
        unsigned short* B = (idx < ZR3) ? Ah2 : Al2;
        int off = (idx < ZR3) ? idx : idx - ZR3;
        B[(size_t)N_NODES * KP2 + off] = 0;
    } else {
        idx -= 2 * ZR3;
        if (idx < N_NODES) hs2[idx] = 0.f;
        else hd2[idx - N_NODES] = 0.f;
    }
}

// ---------------- layer-1 node scores: hs1[i] = x_i . u1, hd1[i] = x_i . v1 ----------------

__global__ void node_scores_x(const float* __restrict__ x, const float* __restrict__ u1,
                              const float* __restrict__ v1, float* __restrict__ hs,
                              float* __restrict__ hd) {
    int wid  = (int)((blockIdx.x * blockDim.x + threadIdx.x) >> 6);
    int lane = threadIdx.x & 63;
    if (wid >= N_NODES) return;
    const float* row = x + (size_t)wid * F_IN;
    float s1 = 0.f, s2 = 0.f;
    for (int k = lane; k < F_IN; k += 64) {
        float v = row[k];
        s1 += v * u1[k];
        s2 += v * v1[k];
    }
    #pragma unroll
    for (int o = 32; o; o >>= 1) { s1 += __shfl_xor(s1, o); s2 += __shfl_xor(s2, o); }
    if (lane == 0) { hs[wid] = s1; hd[wid] = s2; }
}

// ---------------- layer-1 aggregate over raw x (300-wide), LDS weight cache ----------------

__global__ __launch_bounds__(256) void aggregate_x(
        const float* __restrict__ x, const float* __restrict__ hs,
        const float* __restrict__ hd, const int* __restrict__ offs,
        const int* __restrict__ ssrc, _Float16* __restrict__ outh,
        _Float16* __restrict__ outl) {
    int i = blockIdx.x;
    int t = threadIdx.x;
    int lane = t & 63;
    int wv = t >> 6;
    int start = offs[i], end = offs[i + 1];
    __shared__ float red[8];
    __shared__ float part[2][75][5];
    __shared__ float wcache[WCAP];
    float hdi = hd[i];

    float lmax = -INFINITY;
    for (int p = start + t; p < end; p += 256) {
        float s = hs[ssrc[p]] + hdi;
        s = (s >= 0.f) ? s : s * NEG_SLOPE;
        lmax = fmaxf(lmax, s);
    }
    #pragma unroll
    for (int o = 32; o; o >>= 1) lmax = fmaxf(lmax, __shfl_xor(lmax, o));
    if (lane == 0) red[wv] = lmax;
    __syncthreads();
    float m = fmaxf(fmaxf(red[0], red[1]), fmaxf(red[2], red[3]));

    float lsum = 0.f;
    for (int p = start + t; p < end; p += 256) {
        float s = hs[ssrc[p]] + hdi;
        s = (s >= 0.f) ? s : s * NEG_SLOPE;
        float ex = __expf(s - m);
        int q = p - start;
        if (q < WCAP) wcache[q] = ex;
        lsum += ex;
    }
    #pragma unroll
    for (int o = 32; o; o >>= 1) lsum += __shfl_xor(lsum, o);
    if (lane == 0) red[4 + wv] = lsum;
    __syncthreads();
    float inv = 1.0f / (red[4] + red[5] + red[6] + red[7]);
    bool cached = (end - start) <= WCAP;

    int g = t / 75;
    int s = t - g * 75;
    int c = s * 4;
    float4 a = {0.f, 0.f, 0.f, 0.f};
    if (t < 225) {
        int p = start + g;
        for (; p + 3 < end; p += 6) {
            int j0 = ssrc[p], j1 = ssrc[p + 3];
            float w0, w1;
            if (cached) { w0 = wcache[p - start]; w1 = wcache[p + 3 - start]; }
            else {
                float s0 = hs[j0] + hdi; s0 = (s0 >= 0.f) ? s0 : s0 * NEG_SLOPE;
                float s1 = hs[j1] + hdi; s1 = (s1 >= 0.f) ? s1 : s1 * NEG_SLOPE;
                w0 = __expf(s0 - m); w1 = __expf(s1 - m);
            }
            float4 v0 = *(const float4*)(x + (size_t)j0 * F_IN + c);
            float4 v1 = *(const float4*)(x + (size_t)j1 * F_IN + c);
            a.x += w0 * v0.x + w1 * v1.x;
            a.y += w0 * v0.y + w1 * v1.y;
            a.z += w0 * v0.z + w1 * v1.z;
            a.w += w0 * v0.w + w1 * v1.w;
        }
        if (p < end) {
            int j0 = ssrc[p];
            float w0;
            if (cached) w0 = wcache[p - start];
            else {
                float s0 = hs[j0] + hdi; s0 = (s0 >= 0.f) ? s0 : s0 * NEG_SLOPE;
                w0 = __expf(s0 - m);
            }
            float4 v0 = *(const float4*)(x + (size_t)j0 * F_IN + c);
            a.x += w0 * v0.x; a.y += w0 * v0.y; a.z += w0 * v0.z; a.w += w0 * v0.w;
        }
    }
    if (t < 225 && g > 0) {
        part[g - 1][s][0] = a.x; part[g - 1][s][1] = a.y;
        part[g - 1][s][2] = a.z; part[g - 1][s][3] = a.w;
    }
    __syncthreads();
    if (t < 75) {
        a.x += part[0][t][0] + part[1][t][0];
        a.y += part[0][t][1] + part[1][t][1];
        a.z += part[0][t][2] + part[1][t][2];
        a.w += part[0][t][3] + part[1][t][3];
        float rv[4] = {a.x * inv, a.y * inv, a.z * inv, a.w * inv};
        _Float16 hi4[4], lo4[4];
        #pragma unroll
        for (int q = 0; q < 4; ++q) {
            _Float16 hi = (_Float16)rv[q];
            hi4[q] = hi;
            lo4[q] = (_Float16)(rv[q] - (float)hi);
        }
        *(float2*)(outh + (size_t)i * KP1 + c) = *(float2*)hi4;
        *(float2*)(outl + (size_t)i * KP1 + c) = *(float2*)lo4;
    }
}

// ---------------- layer-2 aggregate over fp16 emb1, weight cache + padded reduce ----------------

__global__ __launch_bounds__(256) void aggregate_d(
        const _Float16* __restrict__ h, const float* __restrict__ hs,
        const float* __restrict__ hd, const int* __restrict__ offs,
        const int* __restrict__ ssrc, _Float16* __restrict__ outh,
        _Float16* __restrict__ outl) {
    int i = blockIdx.x;
    int t = threadIdx.x;
    int lane = t & 63;
    int wv = t >> 6;
    int start = offs[i], end = offs[i + 1];
    __shared__ float red[8];
    __shared__ float part[128][9];
    __shared__ float wcache[WCAP];
    float hdi = hd[i];

    float lmax = -INFINITY;
    for (int p = start + t; p < end; p += 256) {
        float s = hs[ssrc[p]] + hdi;
        s = (s >= 0.f) ? s : s * NEG_SLOPE;
        lmax = fmaxf(lmax, s);
    }
    #pragma unroll
    for (int o = 32; o; o >>= 1) lmax = fmaxf(lmax, __shfl_xor(lmax, o));
    if (lane == 0) red[wv] = lmax;
    __syncthreads();
    float m = fmaxf(fmaxf(red[0], red[1]), fmaxf(red[2], red[3]));

    float lsum = 0.f;
    for (int p = start + t; p < end; p += 256) {
        float s = hs[ssrc[p]] + hdi;
        s = (s >= 0.f) ? s : s * NEG_SLOPE;
        float ex = __expf(s - m);
        int q = p - start;
        if (q < WCAP) wcache[q] = ex;
        lsum += ex;
    }
    #pragma unroll
    for (int o = 32; o; o >>= 1) lsum += __shfl_xor(lsum, o);
    if (lane == 0) red[4 + wv] = lsum;
    __syncthreads();
    float inv = 1.0f / (red[4] + red[5] + red[6] + red[7]);
    bool cached = (end - start) <= WCAP;

    int g = t >> 7;            // edge-group 0/1
    int s = t & 127;           // 128 col-slots x 8 f16
    int c = s * 8;
    float a0[8] = {}, a1[8] = {}, a2[8] = {}, a3[8] = {};
    int p = start + g;
    for (; p + 6 < end; p += 8) {
        int j0 = ssrc[p], j1 = ssrc[p + 2], j2 = ssrc[p + 4], j3 = ssrc[p + 6];
        float w0, w1, w2, w3;
        if (cached) {
            int q = p - start;
            w0 = wcache[q]; w1 = wcache[q + 2]; w2 = wcache[q + 4]; w3 = wcache[q + 6];
        } else {
            float s0 = hs[j0] + hdi; s0 = (s0 >= 0.f) ? s0 : s0 * NEG_SLOPE;
            float s1 = hs[j1] + hdi; s1 = (s1 >= 0.f) ? s1 : s1 * NEG_SLOPE;
            float s2 = hs[j2] + hdi; s2 = (s2 >= 0.f) ? s2 : s2 * NEG_SLOPE;
            float s3 = hs[j3] + hdi; s3 = (s3 >= 0.f) ? s3 : s3 * NEG_SLOPE;
            w0 = __expf(s0 - m); w1 = __expf(s1 - m);
            w2 = __expf(s2 - m); w3 = __expf(s3 - m);
        }
        f16x8 v0 = *(const f16x8*)(h + (size_t)j0 * D + c);
        f16x8 v1 = *(const f16x8*)(h + (size_t)j1 * D + c);
        f16x8 v2 = *(const f16x8*)(h + (size_t)j2 * D + c);
        f16x8 v3 = *(const f16x8*)(h + (size_t)j3 * D + c);
        #pragma unroll
        for (int q = 0; q < 8; ++q) {
            a0[q] += w0 * (float)v0[q];
            a1[q] += w1 * (float)v1[q];
            a2[q] += w2 * (float)v2[q];
            a3[q] += w3 * (float)v3[q];
        }
    }
    for (; p < end; p += 2) {
        int j0 = ssrc[p];
        float w0;
        if (cached) w0 = wcache[p - start];
        else {
            float s0 = hs[j0] + hdi; s0 = (s0 >= 0.f) ? s0 : s0 * NEG_SLOPE;
            w0 = __expf(s0 - m);
        }
        f16x8 v0 = *(const f16x8*)(h + (size_t)j0 * D + c);
        #pragma unroll
        for (int q = 0; q < 8; ++q) a0[q] += w0 * (float)v0[q];
    }
    float af[8];
    #pragma unroll
    for (int q = 0; q < 8; ++q) af[q] = (a0[q] + a1[q]) + (a2[q] + a3[q]);
    if (g == 1) {
        #pragma unroll
        for (int q = 0; q < 8; ++q) part[s][q] = af[q];
    }
    __syncthreads();
    if (t < 128) {
        _Float16 hi8[8], lo8[8];
        #pragma unroll
        for (int q = 0; q < 8; ++q) {
            float rv = (af[q] + part[t][q]) * inv;
            _Float16 hi = (_Float16)rv;
            hi8[q] = hi;
            lo8[q] = (_Float16)(rv - (float)hi);
        }
        *(float4*)(outh + (size_t)i * KP2 + c) = *(float4*)hi8;
        *(float4*)(outl + (size_t)i * KP2 + c) = *(float4*)lo8;
    }
}

// ---------------- split-fp16 MFMA GEMM, depth-2 pipeline (3 bufs, counted vmcnt) ----------------
// T3/T4 minimal: STAGE(k+2) issued during compute(k); per-wave counted
// s_waitcnt vmcnt(12/6/0) + raw s_barrier instead of __syncthreads, so
// prefetched loads stay in flight across barriers (2 compute phases to land).

__global__ __launch_bounds__(256) void gemm_split_mfma(
        const _Float16* __restrict__ Ah, const _Float16* __restrict__ Al,
        const _Float16* __restrict__ BTh,
        float* __restrict__ Cf, _Float16* __restrict__ Ch,
        const float* __restrict__ bias,
        const float* __restrict__ asrc, const float* __restrict__ adst,
        float* __restrict__ hs, float* __restrict__ hd,
        int Mreal, int Kp, int dots) {
    __shared__ char lds[3 * 24576];          // 3 x {Ah 8K | Al 8K | Bh 8K} = 72 KB
    const int t    = threadIdx.x;
    const int lane = t & 63;
    const int wid  = t >> 6;
    const int chunkg = (int)gridDim.x >> 3;
    const int vid  = ((int)blockIdx.x & 7) * chunkg + ((int)blockIdx.x >> 3);
    const int n0 = (vid & 7) * 128;
    const int m0 = (vid >> 3) * 128;
    const int wr = (wid >> 1) * 64;
    const int wc = (wid & 1) * 64;
    const int fr = lane & 15;
    const int kg = lane >> 4;

    const int r0 = t >> 2, s0 = t & 3;
    const int r1 = r0 + 64;
    const int g0 = (s0 ^ ((r0 >> 1) & 3)) << 3;
    const int g1 = (s0 ^ ((r1 >> 1) & 3)) << 3;
    const size_t oA0 = (size_t)(m0 + r0) * Kp + g0;
    const size_t oA1 = (size_t)(m0 + r1) * Kp + g1;
    const size_t oB0 = (size_t)(n0 + r0) * Kp + g0;
    const size_t oB1 = (size_t)(n0 + r1) * Kp + g1;
    const int ko = (kg ^ ((fr >> 1) & 3)) << 4;

    f32x4 acc[4][4] = {};
    const int nsteps = Kp >> 5;

    auto STAGE = [&](int b, int kb) {
        char* base = lds + b * 24576;
        GLOAD_LDS16(Ah  + oA0 + kb, base + t * 16);
        GLOAD_LDS16(Ah  + oA1 + kb, base + 4096  + t * 16);
        GLOAD_LDS16(Al  + oA0 + kb, base + 8192  + t * 16);
        GLOAD_LDS16(Al  + oA1 + kb, base + 12288 + t * 16);
        GLOAD_LDS16(BTh + oB0 + kb, base + 16384 + t * 16);
        GLOAD_LDS16(BTh + oB1 + kb, base + 20480 + t * 16);
    };

    STAGE(0, 0);
    STAGE(1, 32);

    for (int k = 0; k < nsteps; ++k) {
        if (k + 2 < nsteps) STAGE((k + 2) % 3, (k + 2) << 5);
        int rem = nsteps - 1 - k;               // stages still in flight beyond k
        if (rem >= 2)      asm volatile("s_waitcnt vmcnt(12)" ::: "memory");
        else if (rem == 1) asm volatile("s_waitcnt vmcnt(6)" ::: "memory");
        else               asm volatile("s_waitcnt vmcnt(0)" ::: "memory");
        __builtin_amdgcn_s_barrier();           // all waves' stage-k loads landed
        __builtin_amdgcn_sched_barrier(0);
        char* base = lds + (k % 3) * 24576;
        f16x8 ah[4], al[4], bh[4];
        #pragma unroll
        for (int f = 0; f < 4; ++f) {
            int ra = (wr + f * 16 + fr) * 64 + ko;
            int rb = (wc + f * 16 + fr) * 64 + ko;
            ah[f] = *(const f16x8*)(base + ra);
            al[f] = *(const f16x8*)(base + 8192 + ra);
            bh[f] = *(const f16x8*)(base + 16384 + rb);
        }
        #pragma unroll
        for (int fm = 0; fm < 4; ++fm)
            #pragma unroll
            for (int fn = 0; fn < 4; ++fn)
                acc[fm][fn] = __builtin_amdgcn_mfma_f32_16x16x32_f16(
                    ah[fm], bh[fn], acc[fm][fn], 0, 0, 0);
        #pragma unroll
        for (int fm = 0; fm < 4; ++fm)
            #pragma unroll
            for (int fn = 0; fn < 4; ++fn)
                acc[fm][fn] = __builtin_amdgcn_mfma_f32_16x16x32_f16(
                    al[fm], bh[fn], acc[fm][fn], 0, 0, 0);
        __builtin_amdgcn_s_barrier();           // protect buf k%3 before overwrite
    }

    // epilogue: bias + relu; write fp32 (Cf) or fp16 (Ch)
    float bv[4];
    #pragma unroll
    for (int fn = 0; fn < 4; ++fn) bv[fn] = bias[n0 + wc + fn * 16 + fr];
    #pragma unroll
    for (int fm = 0; fm < 4; ++fm) {
        int mb = m0 + wr + fm * 16 + kg * 4;
        #pragma unroll
        for (int fn = 0; fn < 4; ++fn) {
            int cn = n0 + wc + fn * 16 + fr;
            #pragma unroll
            for (int j = 0; j < 4; ++j) {
                float r = fmaxf(acc[fm][fn][j] + bv[fn], 0.f);
                acc[fm][fn][j] = r;
                int m = mb + j;
                if (m < Mreal) {
                    if (Cf) Cf[(size_t)m * 1024 + cn] = r;
                    else    Ch[(size_t)m * 1024 + cn] = (_Float16)r;
                }
            }
        }
    }

    if (dots) {
        float av[4], dv[4];
        #pragma unroll
        for (int fn = 0; fn < 4; ++fn) {
            int cn = n0 + wc + fn * 16 + fr;
            av[fn] = asrc[cn];
            dv[fn] = adst[cn];
        }
        #pragma unroll
        for (int fm = 0; fm < 4; ++fm) {
            #pragma unroll
            for (int j = 0; j < 4; ++j) {
                float v1 = acc[fm][0][j] * av[0] + acc[fm][1][j] * av[1]
                         + acc[fm][2][j] * av[2] + acc[fm][3][j] * av[3];
                float v2 = acc[fm][0][j] * dv[0] + acc[fm][1][j] * dv[1]
                         + acc[fm][2][j] * dv[2] + acc[fm][3][j] * dv[3];
                #pragma unroll
                for (int o = 1; o < 16; o <<= 1) {
                    v1 += __shfl_xor(v1, o);
                    v2 += __shfl_xor(v2, o);
                }
                int m = m0 + wr + fm * 16 + kg * 4 + j;
                if (fr == 0 && m < Mreal) {
                    atomicAdd(&hs[m], v1);
                    atomicAdd(&hd[m], v2);
                }
            }
        }
    }
}

// ---------------- final fc + softmax (fp16 emb input) ----------------

__global__ void fc_softmax(const _Float16* __restrict__ emb, const float* __restrict__ fcw,
                           const float* __restrict__ fcb, float* __restrict__ out) {
    int wid  = (int)((blockIdx.x * blockDim.x + threadIdx.x) >> 6);
    int lane = threadIdx.x & 63;
    if (wid >= N_NODES) return;
    float acc[N_CLS] = {};
    const _Float16* row = emb + (size_t)wid * D;
    for (int k = lane * 8; k < D; k += 512) {
        f16x8 v = *(const f16x8*)(row + k);
        #pragma unroll
        for (int q = 0; q < 8; ++q) {
            float vv = (float)v[q];
            #pragma unroll
            for (int c = 0; c < N_CLS; ++c) acc[c] += vv * fcw[(k + q) * N_CLS + c];
        }
    }
    #pragma unroll
    for (int c = 0; c < N_CLS; ++c) {
        #pragma unroll
        for (int o = 32; o; o >>= 1) acc[c] += __shfl_xor(acc[c], o);
    }
    if (lane == 0) {
        float logit[N_CLS];
        float m = -INFINITY;
        #pragma unroll
        for (int c = 0; c < N_CLS; ++c) { logit[c] = acc[c] + fcb[c]; m = fmaxf(m, logit[c]); }
        float s = 0.f;
        #pragma unroll
        for (int c = 0; c < N_CLS; ++c) { logit[c] = __expf(logit[c] - m); s += logit[c]; }
        float invs = 1.0f / s;
        #pragma unroll
        for (int c = 0; c < N_CLS; ++c) out[(size_t)wid * N_CLS + c] = logit[c] * invs;
    }
}

// ---------------- launch ----------------

extern "C" void kernel_launch(void* const* d_in, const int* in_sizes, int n_in,
                              void* d_out, int out_size, void* d_ws, size_t ws_size,
                              hipStream_t stream) {
    const float* x        = (const float*)d_in[0];
    const int*   ei       = (const int*)d_in[1];
    const float* W1       = (const float*)d_in[2];
    const float* att_src1 = (const float*)d_in[3];
    const float* att_dst1 = (const float*)d_in[4];
    const float* b1       = (const float*)d_in[5];
    const float* W2       = (const float*)d_in[6];
    const float* att_src2 = (const float*)d_in[7];
    const float* att_dst2 = (const float*)d_in[8];
    const float* b2       = (const float*)d_in[9];
    const float* fc_w     = (const float*)d_in[10];
    const float* fc_b     = (const float*)d_in[11];
    float* out = (float*)d_out;

    const int* src = ei;
    const int* dst = ei + N_EDGES;

    char* w = (char*)d_ws;
    #define ALLOC(name, bytes) char* name = w; w += (((size_t)(bytes) + 255) & ~(size_t)255)
    ALLOC(p_emb1h, (size_t)N_NODES * D * 2);           // emb1 fp16 (gather source)
    ALLOC(p_emb2h, (size_t)N_NODES * D * 2);           // emb2 fp16 (fc input)
    ALLOC(p_hs1,   (size_t)N_NODES * 4);
    ALLOC(p_hd1,   (size_t)N_NODES * 4);
    ALLOC(p_hs2,   (size_t)N_NODES * 4);
    ALLOC(p_hd2,   (size_t)N_NODES * 4);
    ALLOC(p_deg,   (size_t)N_NODES * 4);
    ALLOC(p_offs,  (size_t)(N_NODES + 1) * 4);
    ALLOC(p_pos,   (size_t)N_NODES * 4);
    ALLOC(p_ssrc,  (size_t)E_TOT * 4);
    ALLOC(p_u1,    (size_t)F_IN * 4);
    ALLOC(p_v1,    (size_t)F_IN * 4);
    ALLOC(p_u2,    (size_t)D * 4);
    ALLOC(p_v2,    (size_t)D * 4);
    ALLOC(p_as1,   (size_t)2 * MP * KP1 * 2);          // Ah1|Al1 fp16 planes
    ALLOC(p_as2,   (size_t)2 * MP * KP2 * 2);          // Ah2|Al2 fp16 planes
    ALLOC(p_bt1,   (size_t)D * KP1 * 2);               // BT1h fp16
    ALLOC(p_bt2,   (size_t)D * KP2 * 2);               // BT2h fp16
    #undef ALLOC

    _Float16* emb1h = (_Float16*)p_emb1h;
    _Float16* emb2h = (_Float16*)p_emb2h;
    float* hs1  = (float*)p_hs1;
    float* hd1  = (float*)p_hd1;
    float* hs2  = (float*)p_hs2;
    float* hd2  = (float*)p_hd2;
    int*   deg  = (int*)p_deg;
    int*   offs = (int*)p_offs;
    int*   pos  = (int*)p_pos;
    int*   ssrc = (int*)p_ssrc;
    float* u1 = (float*)p_u1; float* v1 = (float*)p_v1;
    float* u2 = (float*)p_u2; float* v2 = (float*)p_v2;
    _Float16* Ah1  = (_Float16*)p_as1;
    _Float16* Al1  = Ah1 + (size_t)MP * KP1;
    _Float16* Ah2  = (_Float16*)p_as2;
    _Float16* Al2  = Ah2 + (size_t)MP * KP2;
    _Float16* BT1h = (_Float16*)p_bt1;
    _Float16* BT2h = (_Float16*)p_bt2;

    // prep (uv, transposes, zeros, deg init) in one zone-dispatched launch
    mega_prep<<<ZONE_A + ZONE_B + ZONE_C + ZONE_D, 256, 0, stream>>>(
        W1, att_src1, att_dst1, W2, att_src2, att_dst2,
        u1, v1, u2, v2, BT1h, BT2h, hs2, hd2,
        (unsigned short*)Ah1, (unsigned short*)Al1,
        (unsigned short*)Ah2, (unsigned short*)Al2, deg);

    // CSR build
    count_edges<<<(N_EDGES + 255) / 256, 256, 0, stream>>>(dst, deg);
    scan_offs<<<1, 1024, 0, stream>>>(deg, offs, pos);
    scatter_edges<<<(E_TOT + 255) / 256, 256, 0, stream>>>(src, dst, pos, ssrc);

    const int gemmGrid = (D / 128) * (MP / 128);   // 632 = 8*79

    // layer 1: scores, aggregate x, GEMM -> fp16 emb1 (+b1, relu, fused layer-2 dots)
    node_scores_x<<<(N_NODES * 64 + 255) / 256, 256, 0, stream>>>(x, u1, v1, hs1, hd1);
    aggregate_x<<<N_NODES, 256, 0, stream>>>(x, hs1, hd1, offs, ssrc, Ah1, Al1);
    gemm_split_mfma<<<gemmGrid, 256, 0, stream>>>(Ah1, Al1, BT1h,
                                                  (float*)nullptr, emb1h, b1,
                                                  u2, v2, hs2, hd2, N_NODES, KP1, 1);

    // layer 2: aggregate fp16 emb1, GEMM -> fp16 emb2 (+b2, relu)
    aggregate_d<<<N_NODES, 256, 0, stream>>>(emb1h, hs2, hd2, offs, ssrc, Ah2, Al2);
    gemm_split_mfma<<<gemmGrid, 256, 0, stream>>>(Ah2, Al2, BT2h,
                                                  (float*)nullptr, emb2h, b2,
                                                  (const float*)nullptr, (const float*)nullptr,
                                                  (float*)nullptr, (float*)nullptr,
                                                  N_NODES, KP2, 0);

    // classifier
    fc_softmax<<<(N_NODES * 64 + 255) / 256, 256, 0, stream>>>(emb2h, fc_w, fc_b, out);
}